// Round 5
// baseline (36989.490 us; speedup 1.0000x reference)
//
#include <hip/hip_runtime.h>
#include <math.h>

#define TT 2048
#define II 128
#define NN 1024
#define NWG 256        // 64 i-blocks x 4 j-groups
#define NTHR 512

// Thread mapping (512 = 32 ksplit x 4 rowgroups x 4 batchpairs):
//   ks = tid[0:4]  : k-split lane, owns k in [ks*32, ks*32+32)
//   rt = tid[5:6]  : row group, owns rows ig*16 + rt*4 + {0..3}
//   bt = tid[7:8]  : batch pair, owns batches jg*8 + bt*2 + {0,1}
// Each thread: 4 rows x 2 batches x 32 k -> 256 FMA per 256 LDS bytes (ratio 1.0)
//
// __launch_bounds__(512, 1): R4 used (512, 2) and the VGPR cap STAYED 128 --
// this toolchain treats the 2nd arg like CUDA's min-BLOCKS-per-SM (2 blocks x
// 8 waves / 4 SIMD = 4 waves/EU -> cap 128 -> ~90 spilled regs -> 45 GB scratch
// traffic). With 1: min-blocks reading gives 2 waves/EU -> cap 256; min-waves
// reading gives cap 512, clamped to 256 by the 8-wave workgroup feasibility.
// Demand is ~220 VGPR -> fits either way, zero spill.

__global__ __launch_bounds__(NTHR, 1) void esn_kernel(
    const float* __restrict__ u, const float* __restrict__ w_in,
    const float* __restrict__ w, const float* __restrict__ w_bias,
    float* __restrict__ out, unsigned int* __restrict__ flags)
{
    // h staged per step, XOR-swizzled: word = bl*1024 + (k ^ ((k>>5 & 7)<<2))
    __shared__ alignas(16) float h_stage[8 * 1024];  // 32 KB

    const int tid = threadIdx.x;
    const int wg  = blockIdx.x;
    const int ig  = wg & 63;
    const int jg  = wg >> 6;
    const int ks  = tid & 31;
    const int rt  = (tid >> 5) & 3;
    const int bt  = (tid >> 7) & 3;
    const int lane = tid & 63;

    // ---- persistent register state ----
    float4 wreg[4][8];   // W[4 rows][k-chunk 32] = 128 VGPR
    float4 wir[4];       // W_in[4 rows][ks*4 .. +4)
    float  bias[4];
    #pragma unroll
    for (int rr = 0; rr < 4; ++rr) {
        const int n = ig * 16 + rt * 4 + rr;
        const float* wrow = w + (size_t)n * NN + ks * 32;
        #pragma unroll
        for (int q = 0; q < 8; ++q)
            wreg[rr][q] = reinterpret_cast<const float4*>(wrow)[q];
        wir[rr]  = *reinterpret_cast<const float4*>(w_in + n * II + ks * 4);
        bias[rr] = w_bias[n];
    }

    const int bg0 = jg * 8 + bt * 2;
    const int bg1 = bg0 + 1;
    const int n0  = ig * 16 + rt * 4;

    // walking pointers (incremented per step)
    const float* ua0 = u + ((size_t)bg0 * TT) * II + ks * 4;
    const float* ua1 = u + ((size_t)bg1 * TT) * II + ks * 4;
    float* ob0 = out + ((size_t)bg0 * TT) * NN + n0;
    float* ob1 = out + ((size_t)bg1 * TT) * NN + n0;
    // h staging sources: 4 chunks/thread; init for t-1 = 0 minus one step (inc at loop end)
    const float* hp[4];
    int hw[4];  // swizzled LDS word per chunk
    #pragma unroll
    for (int c = 0; c < 4; ++c) {
        int f4 = c * NTHR + tid;       // 0..2047
        int bl = f4 >> 8;              // batch-local 0..7
        int k4 = f4 & 255;             // float4 index in row
        hp[c] = out + ((size_t)(jg * 8 + bl) * TT) * NN + k4 * 4 - NN;
        hw[c] = bl * 1024 + ((k4 * 4) ^ (((k4 >> 3) & 7) << 2));
    }
    // main-loop LDS read bases (swizzle applied per-q)
    const int swz    = (ks & 7) << 2;
    const int base0  = (bt * 2 + 0) * 1024 + ks * 32;
    const int base1  = (bt * 2 + 1) * 1024 + ks * 32;

    unsigned int* gflags = flags + jg * 64;

    for (int t = 0; t < TT; ++t) {
        // -- issue u loads (overlap the poll) --
        float4 u0, u1;
        asm volatile("global_load_dwordx4 %0, %1, off" : "=v"(u0) : "v"(ua0));
        asm volatile("global_load_dwordx4 %0, %1, off" : "=v"(u1) : "v"(ua1));

        float4 h0, h1, h2, h3;
        if (t > 0) {
            for (;;) {
                unsigned int v = __hip_atomic_load(&gflags[lane], __ATOMIC_RELAXED,
                                                   __HIP_MEMORY_SCOPE_AGENT);
                if (__all((int)(v >= (unsigned)t))) break;
                __builtin_amdgcn_s_sleep(1);
            }
            asm volatile("" ::: "memory");
            // h_{t-1} -> regs, IC-coherent (sc1), 4x dwordx4 per thread
            asm volatile("global_load_dwordx4 %0, %1, off sc1" : "=v"(h0) : "v"(hp[0]));
            asm volatile("global_load_dwordx4 %0, %1, off sc1" : "=v"(h1) : "v"(hp[1]));
            asm volatile("global_load_dwordx4 %0, %1, off sc1" : "=v"(h2) : "v"(hp[2]));
            asm volatile("global_load_dwordx4 %0, %1, off sc1" : "=v"(h3) : "v"(hp[3]));
            asm volatile("s_waitcnt vmcnt(4)" ::: "memory");  // u retired, h in flight
            __builtin_amdgcn_sched_barrier(0);
        } else {
            asm volatile("s_waitcnt vmcnt(0)" ::: "memory");
            __builtin_amdgcn_sched_barrier(0);
        }

        // -- W_in . u partial (hides h load latency) --
        float acc00 = wir[0].x*u0.x + wir[0].y*u0.y + wir[0].z*u0.z + wir[0].w*u0.w;
        float acc10 = wir[1].x*u0.x + wir[1].y*u0.y + wir[1].z*u0.z + wir[1].w*u0.w;
        float acc20 = wir[2].x*u0.x + wir[2].y*u0.y + wir[2].z*u0.z + wir[2].w*u0.w;
        float acc30 = wir[3].x*u0.x + wir[3].y*u0.y + wir[3].z*u0.z + wir[3].w*u0.w;
        float acc01 = wir[0].x*u1.x + wir[0].y*u1.y + wir[0].z*u1.z + wir[0].w*u1.w;
        float acc11 = wir[1].x*u1.x + wir[1].y*u1.y + wir[1].z*u1.z + wir[1].w*u1.w;
        float acc21 = wir[2].x*u1.x + wir[2].y*u1.y + wir[2].z*u1.z + wir[2].w*u1.w;
        float acc31 = wir[3].x*u1.x + wir[3].y*u1.y + wir[3].z*u1.z + wir[3].w*u1.w;

        if (t > 0) {
            asm volatile("s_waitcnt vmcnt(0)" ::: "memory");  // h regs ready
            __builtin_amdgcn_sched_barrier(0);
        }
        __syncthreads();            // S1a: orders h_stage writes vs prior-step reads
        if (t > 0) {
            *reinterpret_cast<float4*>(&h_stage[hw[0]]) = h0;
            *reinterpret_cast<float4*>(&h_stage[hw[1]]) = h1;
            *reinterpret_cast<float4*>(&h_stage[hw[2]]) = h2;
            *reinterpret_cast<float4*>(&h_stage[hw[3]]) = h3;
        }
        __syncthreads();            // S1b: h_stage visible to all

        // -- main W . h loop: 16 ds_read_b128 + 256 FMA per thread --
        if (t > 0) {
            #pragma unroll
            for (int q = 0; q < 8; ++q) {
                const int o = (q * 4) ^ swz;
                float4 hv0 = *reinterpret_cast<const float4*>(&h_stage[base0 + o]);
                float4 hv1 = *reinterpret_cast<const float4*>(&h_stage[base1 + o]);
                float4 w0 = wreg[0][q], w1 = wreg[1][q], w2 = wreg[2][q], w3 = wreg[3][q];
                acc00 += w0.x*hv0.x + w0.y*hv0.y + w0.z*hv0.z + w0.w*hv0.w;
                acc10 += w1.x*hv0.x + w1.y*hv0.y + w1.z*hv0.z + w1.w*hv0.w;
                acc20 += w2.x*hv0.x + w2.y*hv0.y + w2.z*hv0.z + w2.w*hv0.w;
                acc30 += w3.x*hv0.x + w3.y*hv0.y + w3.z*hv0.z + w3.w*hv0.w;
                acc01 += w0.x*hv1.x + w0.y*hv1.y + w0.z*hv1.z + w0.w*hv1.w;
                acc11 += w1.x*hv1.x + w1.y*hv1.y + w1.z*hv1.z + w1.w*hv1.w;
                acc21 += w2.x*hv1.x + w2.y*hv1.y + w2.z*hv1.z + w2.w*hv1.w;
                acc31 += w3.x*hv1.x + w3.y*hv1.y + w3.z*hv1.z + w3.w*hv1.w;
            }
        }

        // -- reduce over 32 k-split lanes (bits 0..4) --
        float red[8] = {acc00, acc10, acc20, acc30, acc01, acc11, acc21, acc31};
        #pragma unroll
        for (int i = 0; i < 8; ++i) {
            float a = red[i];
            a += __shfl_xor(a, 1);
            a += __shfl_xor(a, 2);
            a += __shfl_xor(a, 4);
            a += __shfl_xor(a, 8);
            a += __shfl_xor(a, 16);
            red[i] = a;
        }

        if (ks == 0) {
            #pragma unroll
            for (int rr = 0; rr < 4; ++rr) {
                float hv0 = tanhf(red[rr]     + bias[rr]);
                float hv1 = tanhf(red[4 + rr] + bias[rr]);
                __hip_atomic_store(ob0 + (size_t)t * NN + rr, hv0,
                                   __ATOMIC_RELAXED, __HIP_MEMORY_SCOPE_AGENT);
                __hip_atomic_store(ob1 + (size_t)t * NN + rr, hv1,
                                   __ATOMIC_RELAXED, __HIP_MEMORY_SCOPE_AGENT);
            }
        }

        asm volatile("s_waitcnt vmcnt(0)" ::: "memory");  // all h_t stores durable
        __syncthreads();                                  // S2: whole WG drained
        if (tid == 0) {
            __hip_atomic_store(&gflags[ig], (unsigned)(t + 1),
                               __ATOMIC_RELAXED, __HIP_MEMORY_SCOPE_AGENT);
        }

        // advance walking pointers
        ua0 += II; ua1 += II;
        #pragma unroll
        for (int c = 0; c < 4; ++c) hp[c] += NN;
    }
}

extern "C" void kernel_launch(void* const* d_in, const int* in_sizes, int n_in,
                              void* d_out, int out_size, void* d_ws, size_t ws_size,
                              hipStream_t stream) {
    const float* u      = (const float*)d_in[0];
    const float* w_in   = (const float*)d_in[1];
    const float* w      = (const float*)d_in[2];
    const float* w_bias = (const float*)d_in[3];
    float* out          = (float*)d_out;
    unsigned int* flags = (unsigned int*)d_ws;

    hipMemsetAsync(flags, 0, 4 * 64 * sizeof(unsigned int), stream);

    // 256 WGs x 512 threads = exactly 1 WG per CU -> co-residency guaranteed,
    // flag spin cannot deadlock.
    esn_kernel<<<dim3(NWG), dim3(NTHR), 0, stream>>>(u, w_in, w, w_bias, out, flags);
}

// Round 7
// 13165.933 us; speedup vs baseline: 2.8095x; 2.8095x over previous
//
#include <hip/hip_runtime.h>
#include <math.h>

#define TT 2048
#define II 128
#define NN 1024
#define NWG 256        // 64 i-blocks x 4 j-groups
#define NTHR 512

// Swizzle: spreads the 16-float k-windows across all 32 LDS banks.
#define SW(k) ((k) ^ ((((k) >> 5) & 7) << 2))

// Thread mapping (512 = 64 ksplit x 4 rowgroups x 2 batchgroups):
//   l  = tid[0:6) : k-split lane, owns k in [l*16, l*16+16)
//   rt = tid[6:8) : rows n0 = ig*16 + rt*4 .. +4
//   bt = tid[8]   : batches jg*8 + bt*4 .. +4
// Per thread/step: 4 rows x 4 batches x 16 k = 256 FMA, 32 ds_read_b128.
// W lives in LDS -> persistent VGPR demand ~90 < the immovable 128 cap.
//
// R6 BUG (absmax 2.0): read offsets were computed as 16*l + ((4q)^X) instead
// of (16*l + 4q)^X. X bit4 = l bit3, and 16*l has bit4 = l&1 -> for lanes with
// (l&1)&(l>>3&1)=1 the add CARRIED into bit5, reading 32 floats off. The XOR
// must be applied to the full k value (bits 0-1 are zero, X only touches 2-4,
// so (16l+4q)^X is exact). Fixed below: o0..o3 are per-lane precomputed.

__global__ __launch_bounds__(NTHR)
__attribute__((amdgpu_waves_per_eu(2, 2)))
void esn_kernel(const float* __restrict__ u, const float* __restrict__ w_in,
                const float* __restrict__ w, const float* __restrict__ w_bias,
                float* __restrict__ out, unsigned int* __restrict__ flags)
{
    __shared__ alignas(16) float w_lds[16 * 1024];   // 64 KB, swizzled, static
    __shared__ alignas(16) float h_stage[8 * 1024];  // 32 KB, swizzled, per step

    const int tid = threadIdx.x;
    const int wg  = blockIdx.x;
    const int ig  = wg & 63;
    const int jg  = wg >> 6;
    const int l   = tid & 63;
    const int rt  = (tid >> 6) & 3;
    const int bt  = tid >> 8;            // 0..1
    const int n0  = ig * 16 + rt * 4;
    const int bgb = jg * 8 + bt * 4;

    // ---- stage W tile into LDS once (coalesced global, swizzled LDS) ----
    #pragma unroll
    for (int c = 0; c < 32; ++c) {
        int idx = c * NTHR + tid;        // 0..16383
        int row = idx >> 10;
        int k   = idx & 1023;
        w_lds[row * 1024 + SW(k)] = w[(size_t)(ig * 16 + row) * NN + k];
    }

    // W_in slice (2 floats/row) + bias, in registers
    float2 wir0 = *reinterpret_cast<const float2*>(w_in + (n0 + 0) * II + 2 * l);
    float2 wir1 = *reinterpret_cast<const float2*>(w_in + (n0 + 1) * II + 2 * l);
    float2 wir2 = *reinterpret_cast<const float2*>(w_in + (n0 + 2) * II + 2 * l);
    float2 wir3 = *reinterpret_cast<const float2*>(w_in + (n0 + 3) * II + 2 * l);
    const float b0 = w_bias[n0 + 0];
    const float b1 = w_bias[n0 + 1];
    const float b2 = w_bias[n0 + 2];
    const float b3 = w_bias[n0 + 3];

    // walking pointers
    const float* up0 = u + (size_t)(bgb + 0) * TT * II + 2 * l;
    const float* up1 = u + (size_t)(bgb + 1) * TT * II + 2 * l;
    const float* up2 = u + (size_t)(bgb + 2) * TT * II + 2 * l;
    const float* up3 = u + (size_t)(bgb + 3) * TT * II + 2 * l;

    const float *hp0, *hp1, *hp2, *hp3;
    int hw0, hw1, hw2, hw3;
    {
        int f4, bl, k4;
        f4 = 0 * NTHR + tid; bl = f4 >> 8; k4 = f4 & 255;
        hp0 = out + (size_t)(jg * 8 + bl) * TT * NN + 4 * k4 - NN;
        hw0 = bl * 1024 + SW(4 * k4);
        f4 = 1 * NTHR + tid; bl = f4 >> 8; k4 = f4 & 255;
        hp1 = out + (size_t)(jg * 8 + bl) * TT * NN + 4 * k4 - NN;
        hw1 = bl * 1024 + SW(4 * k4);
        f4 = 2 * NTHR + tid; bl = f4 >> 8; k4 = f4 & 255;
        hp2 = out + (size_t)(jg * 8 + bl) * TT * NN + 4 * k4 - NN;
        hw2 = bl * 1024 + SW(4 * k4);
        f4 = 3 * NTHR + tid; bl = f4 >> 8; k4 = f4 & 255;
        hp3 = out + (size_t)(jg * 8 + bl) * TT * NN + 4 * k4 - NN;
        hw3 = bl * 1024 + SW(4 * k4);
    }

    // per-lane swizzled read offsets within a row: (16*l + 4q) ^ X, exact XOR
    const int kl = 16 * l;
    const int o0 = SW(kl + 0);
    const int o1 = SW(kl + 4);
    const int o2 = SW(kl + 8);
    const int o3 = SW(kl + 12);
    const int wb = rt * 4 * 1024;    // row base (k part lives in o0..o3)
    const int hb = bt * 4 * 1024;

    unsigned int* gflags = flags + jg * 64;

    __syncthreads();   // w_lds ready

    float acc[4][4];

#define UPART(bb, uv) \
    acc[0][bb] = wir0.x * uv.x + wir0.y * uv.y; \
    acc[1][bb] = wir1.x * uv.x + wir1.y * uv.y; \
    acc[2][bb] = wir2.x * uv.x + wir2.y * uv.y; \
    acc[3][bb] = wir3.x * uv.x + wir3.y * uv.y;

#define DOT(rr, bb, wv, hv) \
    acc[rr][bb] += wv.x*hv.x + wv.y*hv.y + wv.z*hv.z + wv.w*hv.w;

#define QSTEP(o) { \
    float4 wv0 = *reinterpret_cast<const float4*>(&w_lds[wb + 0*1024 + (o)]); \
    float4 wv1 = *reinterpret_cast<const float4*>(&w_lds[wb + 1*1024 + (o)]); \
    float4 wv2 = *reinterpret_cast<const float4*>(&w_lds[wb + 2*1024 + (o)]); \
    float4 wv3 = *reinterpret_cast<const float4*>(&w_lds[wb + 3*1024 + (o)]); \
    float4 hv0 = *reinterpret_cast<const float4*>(&h_stage[hb + 0*1024 + (o)]); \
    float4 hv1 = *reinterpret_cast<const float4*>(&h_stage[hb + 1*1024 + (o)]); \
    float4 hv2 = *reinterpret_cast<const float4*>(&h_stage[hb + 2*1024 + (o)]); \
    float4 hv3 = *reinterpret_cast<const float4*>(&h_stage[hb + 3*1024 + (o)]); \
    DOT(0,0,wv0,hv0) DOT(1,0,wv1,hv0) DOT(2,0,wv2,hv0) DOT(3,0,wv3,hv0) \
    DOT(0,1,wv0,hv1) DOT(1,1,wv1,hv1) DOT(2,1,wv2,hv1) DOT(3,1,wv3,hv1) \
    DOT(0,2,wv0,hv2) DOT(1,2,wv1,hv2) DOT(2,2,wv2,hv2) DOT(3,2,wv3,hv2) \
    DOT(0,3,wv0,hv3) DOT(1,3,wv1,hv3) DOT(2,3,wv2,hv3) DOT(3,3,wv3,hv3) }

    for (int t = 0; t < TT; ++t) {
        // -- issue u loads (overlap the poll) --
        float2 uv0, uv1, uv2, uv3;
        asm volatile("global_load_dwordx2 %0, %1, off" : "=v"(uv0) : "v"(up0));
        asm volatile("global_load_dwordx2 %0, %1, off" : "=v"(uv1) : "v"(up1));
        asm volatile("global_load_dwordx2 %0, %1, off" : "=v"(uv2) : "v"(up2));
        asm volatile("global_load_dwordx2 %0, %1, off" : "=v"(uv3) : "v"(up3));

        float4 h0, h1, h2, h3;
        if (t > 0) {
            for (;;) {
                unsigned int v = __hip_atomic_load(&gflags[l], __ATOMIC_RELAXED,
                                                   __HIP_MEMORY_SCOPE_AGENT);
                if (__all((int)(v >= (unsigned)t))) break;
                __builtin_amdgcn_s_sleep(1);
            }
            asm volatile("" ::: "memory");
            // h_{t-1} -> regs, IC-coherent (sc1)
            asm volatile("global_load_dwordx4 %0, %1, off sc1" : "=v"(h0) : "v"(hp0));
            asm volatile("global_load_dwordx4 %0, %1, off sc1" : "=v"(h1) : "v"(hp1));
            asm volatile("global_load_dwordx4 %0, %1, off sc1" : "=v"(h2) : "v"(hp2));
            asm volatile("global_load_dwordx4 %0, %1, off sc1" : "=v"(h3) : "v"(hp3));
            asm volatile("s_waitcnt vmcnt(4)" ::: "memory");  // u done, h in flight
            __builtin_amdgcn_sched_barrier(0);
        } else {
            asm volatile("s_waitcnt vmcnt(0)" ::: "memory");
            __builtin_amdgcn_sched_barrier(0);
        }

        // -- W_in . u partial (hides h load latency) --
        UPART(0, uv0) UPART(1, uv1) UPART(2, uv2) UPART(3, uv3)

        if (t > 0) {
            asm volatile("s_waitcnt vmcnt(0)" ::: "memory");  // h regs ready
            __builtin_amdgcn_sched_barrier(0);
            *reinterpret_cast<float4*>(&h_stage[hw0]) = h0;
            *reinterpret_cast<float4*>(&h_stage[hw1]) = h1;
            *reinterpret_cast<float4*>(&h_stage[hw2]) = h2;
            *reinterpret_cast<float4*>(&h_stage[hw3]) = h3;
        }
        __syncthreads();   // S_mid: h_stage visible (prev-step reads already
                           // ordered before this step's writes by S_end of t-1)

        // -- main W.h loop: 32 ds_read_b128 + 256 FMA per thread --
        if (t > 0) {
            QSTEP(o0) QSTEP(o1) QSTEP(o2) QSTEP(o3)
        }

        // -- reduce: butterfly over lane bits 0..3 (16-lane k-subgroups) --
        #pragma unroll
        for (int rr = 0; rr < 4; ++rr)
            #pragma unroll
            for (int bb = 0; bb < 4; ++bb) {
                float a = acc[rr][bb];
                a += __shfl_xor(a, 1);
                a += __shfl_xor(a, 2);
                a += __shfl_xor(a, 4);
                a += __shfl_xor(a, 8);
                acc[rr][bb] = a;
            }

        // -- select tree: lane m (=l&15) takes output (rr = m&3, bb = m>>2) --
        const int m = l & 15;
        float c00 = (m & 1) ? acc[1][0] : acc[0][0];
        float c01 = (m & 1) ? acc[3][0] : acc[2][0];
        float c10 = (m & 1) ? acc[1][1] : acc[0][1];
        float c11 = (m & 1) ? acc[3][1] : acc[2][1];
        float c20 = (m & 1) ? acc[1][2] : acc[0][2];
        float c21 = (m & 1) ? acc[3][2] : acc[2][2];
        float c30 = (m & 1) ? acc[1][3] : acc[0][3];
        float c31 = (m & 1) ? acc[3][3] : acc[2][3];
        float d0 = (m & 2) ? c01 : c00;
        float d1 = (m & 2) ? c11 : c10;
        float d2 = (m & 2) ? c21 : c20;
        float d3 = (m & 2) ? c31 : c30;
        float e0 = (m & 4) ? d1 : d0;
        float e1 = (m & 4) ? d3 : d2;
        float v  = (m & 8) ? e1 : e0;
        // sum the four 16-lane k-subgroups
        v += __shfl_xor(v, 16);
        v += __shfl_xor(v, 32);

        if (l < 16) {
            float bs = (m & 2) ? ((m & 1) ? b3 : b2) : ((m & 1) ? b1 : b0);
            int rr = m & 3;
            int bb = m >> 2;
            float hval = tanhf(v + bs);
            __hip_atomic_store(out + ((size_t)(bgb + bb) * TT + t) * NN + (n0 + rr),
                               hval, __ATOMIC_RELAXED, __HIP_MEMORY_SCOPE_AGENT);
        }

        asm volatile("s_waitcnt vmcnt(0)" ::: "memory");  // h_t stores durable
        __syncthreads();                                  // S_end: WG drained
        if (tid == 0) {
            __hip_atomic_store(&gflags[ig], (unsigned)(t + 1),
                               __ATOMIC_RELAXED, __HIP_MEMORY_SCOPE_AGENT);
        }

        up0 += II; up1 += II; up2 += II; up3 += II;
        hp0 += NN; hp1 += NN; hp2 += NN; hp3 += NN;
    }
#undef UPART
#undef DOT
#undef QSTEP
}

extern "C" void kernel_launch(void* const* d_in, const int* in_sizes, int n_in,
                              void* d_out, int out_size, void* d_ws, size_t ws_size,
                              hipStream_t stream) {
    const float* u      = (const float*)d_in[0];
    const float* w_in   = (const float*)d_in[1];
    const float* w      = (const float*)d_in[2];
    const float* w_bias = (const float*)d_in[3];
    float* out          = (float*)d_out;
    unsigned int* flags = (unsigned int*)d_ws;

    hipMemsetAsync(flags, 0, 4 * 64 * sizeof(unsigned int), stream);

    // 256 WGs x 512 threads, 96 KB LDS = exactly 1 WG/CU -> co-residency
    // guaranteed, flag spin cannot deadlock.
    esn_kernel<<<dim3(NWG), dim3(NTHR), 0, stream>>>(u, w_in, w, w_bias, out, flags);
}

// Round 12
// 11966.130 us; speedup vs baseline: 3.0912x; 1.1003x over previous
//
#include <hip/hip_runtime.h>
#include <math.h>

#define TT 2048
#define II 128
#define NN 1024
#define NWG 256        // 64 i-blocks x 4 j-groups
#define NTHR 512

// Swizzle: spreads the 16-float k-windows across all 32 LDS banks.
#define SW(k) ((k) ^ ((((k) >> 5) & 7) << 2))

// Base = R7 (passed, 13.2 ms). Deltas, both mechanically verified:
//  1. S1a barrier removed: S2 of step t-1 already orders every wave's QSTEP
//     reads of h_stage before any wave's step-t ds_writes (full barrier between
//     them on all paths) -> 2 barriers/step.
//  2. Reduction levels xor1/xor2/xor8 moved from shfl (LDS pipe) to DPP VALU
//     adds (quad_perm 0xB1 / 0x4E, row_ror:8 == xor8 within row-16; exact
//     pairwise sums, all lanes valid). LDS-pipe ops/thread: 66 -> 18.
// R8-R11 lesson recorded: redesigns that raise register pressure around
// inline-asm loads corrupt silently; R7's 116-VGPR structure is the safe base.

__device__ __forceinline__ float dpp_add_xor1(float x) {  // quad_perm [1,0,3,2]
    int y = __builtin_amdgcn_update_dpp(0, __float_as_int(x), 0xB1, 0xF, 0xF, true);
    return x + __int_as_float(y);
}
__device__ __forceinline__ float dpp_add_xor2(float x) {  // quad_perm [2,3,0,1]
    int y = __builtin_amdgcn_update_dpp(0, __float_as_int(x), 0x4E, 0xF, 0xF, true);
    return x + __int_as_float(y);
}
__device__ __forceinline__ float dpp_add_xor8(float x) {  // row_ror:8 (xor8 in row16)
    int y = __builtin_amdgcn_update_dpp(0, __float_as_int(x), 0x128, 0xF, 0xF, true);
    return x + __int_as_float(y);
}

__global__ __launch_bounds__(NTHR)
__attribute__((amdgpu_waves_per_eu(2, 2)))
void esn_kernel(const float* __restrict__ u, const float* __restrict__ w_in,
                const float* __restrict__ w, const float* __restrict__ w_bias,
                float* __restrict__ out, unsigned int* __restrict__ flags)
{
    __shared__ alignas(16) float w_lds[16 * 1024];   // 64 KB, swizzled, static
    __shared__ alignas(16) float h_stage[8 * 1024];  // 32 KB, swizzled, per step

    const int tid = threadIdx.x;
    const int wg  = blockIdx.x;
    const int ig  = wg & 63;
    const int jg  = wg >> 6;
    const int l   = tid & 63;
    const int rt  = (tid >> 6) & 3;
    const int bt  = tid >> 8;            // 0..1
    const int n0  = ig * 16 + rt * 4;
    const int bgb = jg * 8 + bt * 4;

    // ---- stage W tile into LDS once (coalesced global, swizzled LDS) ----
    #pragma unroll
    for (int c = 0; c < 32; ++c) {
        int idx = c * NTHR + tid;        // 0..16383
        int row = idx >> 10;
        int k   = idx & 1023;
        w_lds[row * 1024 + SW(k)] = w[(size_t)(ig * 16 + row) * NN + k];
    }

    // W_in slice (2 floats/row) + bias, in registers
    float2 wir0 = *reinterpret_cast<const float2*>(w_in + (n0 + 0) * II + 2 * l);
    float2 wir1 = *reinterpret_cast<const float2*>(w_in + (n0 + 1) * II + 2 * l);
    float2 wir2 = *reinterpret_cast<const float2*>(w_in + (n0 + 2) * II + 2 * l);
    float2 wir3 = *reinterpret_cast<const float2*>(w_in + (n0 + 3) * II + 2 * l);
    const float b0 = w_bias[n0 + 0];
    const float b1 = w_bias[n0 + 1];
    const float b2 = w_bias[n0 + 2];
    const float b3 = w_bias[n0 + 3];

    // walking pointers
    const float* up0 = u + (size_t)(bgb + 0) * TT * II + 2 * l;
    const float* up1 = u + (size_t)(bgb + 1) * TT * II + 2 * l;
    const float* up2 = u + (size_t)(bgb + 2) * TT * II + 2 * l;
    const float* up3 = u + (size_t)(bgb + 3) * TT * II + 2 * l;

    const float *hp0, *hp1, *hp2, *hp3;
    int hw0, hw1, hw2, hw3;
    {
        int f4, bl, k4;
        f4 = 0 * NTHR + tid; bl = f4 >> 8; k4 = f4 & 255;
        hp0 = out + (size_t)(jg * 8 + bl) * TT * NN + 4 * k4 - NN;
        hw0 = bl * 1024 + SW(4 * k4);
        f4 = 1 * NTHR + tid; bl = f4 >> 8; k4 = f4 & 255;
        hp1 = out + (size_t)(jg * 8 + bl) * TT * NN + 4 * k4 - NN;
        hw1 = bl * 1024 + SW(4 * k4);
        f4 = 2 * NTHR + tid; bl = f4 >> 8; k4 = f4 & 255;
        hp2 = out + (size_t)(jg * 8 + bl) * TT * NN + 4 * k4 - NN;
        hw2 = bl * 1024 + SW(4 * k4);
        f4 = 3 * NTHR + tid; bl = f4 >> 8; k4 = f4 & 255;
        hp3 = out + (size_t)(jg * 8 + bl) * TT * NN + 4 * k4 - NN;
        hw3 = bl * 1024 + SW(4 * k4);
    }

    // per-lane swizzled read offsets within a row: SW applied to the FULL index
    const int kl = 16 * l;
    const int o0 = SW(kl + 0);
    const int o1 = SW(kl + 4);
    const int o2 = SW(kl + 8);
    const int o3 = SW(kl + 12);
    const int wb = rt * 4 * 1024;    // row base (k part lives in o0..o3)
    const int hb = bt * 4 * 1024;

    unsigned int* gflags = flags + jg * 64;

    __syncthreads();   // w_lds ready

    float acc[4][4];

#define UPART(bb, uv) \
    acc[0][bb] = wir0.x * uv.x + wir0.y * uv.y; \
    acc[1][bb] = wir1.x * uv.x + wir1.y * uv.y; \
    acc[2][bb] = wir2.x * uv.x + wir2.y * uv.y; \
    acc[3][bb] = wir3.x * uv.x + wir3.y * uv.y;

#define DOT(rr, bb, wv, hv) \
    acc[rr][bb] += wv.x*hv.x + wv.y*hv.y + wv.z*hv.z + wv.w*hv.w;

#define QSTEP(o) { \
    float4 wv0 = *reinterpret_cast<const float4*>(&w_lds[wb + 0*1024 + (o)]); \
    float4 wv1 = *reinterpret_cast<const float4*>(&w_lds[wb + 1*1024 + (o)]); \
    float4 wv2 = *reinterpret_cast<const float4*>(&w_lds[wb + 2*1024 + (o)]); \
    float4 wv3 = *reinterpret_cast<const float4*>(&w_lds[wb + 3*1024 + (o)]); \
    float4 hv0 = *reinterpret_cast<const float4*>(&h_stage[hb + 0*1024 + (o)]); \
    float4 hv1 = *reinterpret_cast<const float4*>(&h_stage[hb + 1*1024 + (o)]); \
    float4 hv2 = *reinterpret_cast<const float4*>(&h_stage[hb + 2*1024 + (o)]); \
    float4 hv3 = *reinterpret_cast<const float4*>(&h_stage[hb + 3*1024 + (o)]); \
    DOT(0,0,wv0,hv0) DOT(1,0,wv1,hv0) DOT(2,0,wv2,hv0) DOT(3,0,wv3,hv0) \
    DOT(0,1,wv0,hv1) DOT(1,1,wv1,hv1) DOT(2,1,wv2,hv1) DOT(3,1,wv3,hv1) \
    DOT(0,2,wv0,hv2) DOT(1,2,wv1,hv2) DOT(2,2,wv2,hv2) DOT(3,2,wv3,hv2) \
    DOT(0,3,wv0,hv3) DOT(1,3,wv1,hv3) DOT(2,3,wv2,hv3) DOT(3,3,wv3,hv3) }

    for (int t = 0; t < TT; ++t) {
        // -- issue u loads (overlap the poll) --
        float2 uv0, uv1, uv2, uv3;
        asm volatile("global_load_dwordx2 %0, %1, off" : "=v"(uv0) : "v"(up0));
        asm volatile("global_load_dwordx2 %0, %1, off" : "=v"(uv1) : "v"(up1));
        asm volatile("global_load_dwordx2 %0, %1, off" : "=v"(uv2) : "v"(up2));
        asm volatile("global_load_dwordx2 %0, %1, off" : "=v"(uv3) : "v"(up3));

        float4 h0, h1, h2, h3;
        if (t > 0) {
            for (;;) {
                unsigned int v = __hip_atomic_load(&gflags[l], __ATOMIC_RELAXED,
                                                   __HIP_MEMORY_SCOPE_AGENT);
                if (__all((int)(v >= (unsigned)t))) break;
                __builtin_amdgcn_s_sleep(1);
            }
            asm volatile("" ::: "memory");
            // h_{t-1} -> regs, IC-coherent (sc1)
            asm volatile("global_load_dwordx4 %0, %1, off sc1" : "=v"(h0) : "v"(hp0));
            asm volatile("global_load_dwordx4 %0, %1, off sc1" : "=v"(h1) : "v"(hp1));
            asm volatile("global_load_dwordx4 %0, %1, off sc1" : "=v"(h2) : "v"(hp2));
            asm volatile("global_load_dwordx4 %0, %1, off sc1" : "=v"(h3) : "v"(hp3));
            asm volatile("s_waitcnt vmcnt(4)" ::: "memory");  // u done, h in flight
            __builtin_amdgcn_sched_barrier(0);
        } else {
            asm volatile("s_waitcnt vmcnt(0)" ::: "memory");
            __builtin_amdgcn_sched_barrier(0);
        }

        // -- W_in . u partial (hides h load latency) --
        UPART(0, uv0) UPART(1, uv1) UPART(2, uv2) UPART(3, uv3)

        if (t > 0) {
            asm volatile("s_waitcnt vmcnt(0)" ::: "memory");  // h regs ready
            __builtin_amdgcn_sched_barrier(0);
            // S1a removed: S2 of step t-1 is a full barrier between every
            // wave's QSTEP reads (step t-1) and these writes (step t).
            *reinterpret_cast<float4*>(&h_stage[hw0]) = h0;
            *reinterpret_cast<float4*>(&h_stage[hw1]) = h1;
            *reinterpret_cast<float4*>(&h_stage[hw2]) = h2;
            *reinterpret_cast<float4*>(&h_stage[hw3]) = h3;
        }
        __syncthreads();   // S1b: h_stage visible to all

        // -- main W.h loop: 32 ds_read_b128 + 256 FMA per thread --
        if (t > 0) {
            QSTEP(o0) QSTEP(o1) QSTEP(o2) QSTEP(o3)
        }

        // -- reduce over lane bits 0..3: DPP (VALU) for xor1/2/8, shfl for 4 --
        #pragma unroll
        for (int rr = 0; rr < 4; ++rr)
            #pragma unroll
            for (int bb = 0; bb < 4; ++bb) {
                float a = acc[rr][bb];
                a = dpp_add_xor1(a);
                a = dpp_add_xor2(a);
                a += __shfl_xor(a, 4);
                a = dpp_add_xor8(a);
                acc[rr][bb] = a;
            }

        // -- select tree: lane m (=l&15) takes output (rr = m&3, bb = m>>2) --
        const int m = l & 15;
        float c00 = (m & 1) ? acc[1][0] : acc[0][0];
        float c01 = (m & 1) ? acc[3][0] : acc[2][0];
        float c10 = (m & 1) ? acc[1][1] : acc[0][1];
        float c11 = (m & 1) ? acc[3][1] : acc[2][1];
        float c20 = (m & 1) ? acc[1][2] : acc[0][2];
        float c21 = (m & 1) ? acc[3][2] : acc[2][2];
        float c30 = (m & 1) ? acc[1][3] : acc[0][3];
        float c31 = (m & 1) ? acc[3][3] : acc[2][3];
        float d0 = (m & 2) ? c01 : c00;
        float d1 = (m & 2) ? c11 : c10;
        float d2 = (m & 2) ? c21 : c20;
        float d3 = (m & 2) ? c31 : c30;
        float e0 = (m & 4) ? d1 : d0;
        float e1 = (m & 4) ? d3 : d2;
        float v  = (m & 8) ? e1 : e0;
        // sum the four 16-lane k-subgroups
        v += __shfl_xor(v, 16);
        v += __shfl_xor(v, 32);

        if (l < 16) {
            float bs = (m & 2) ? ((m & 1) ? b3 : b2) : ((m & 1) ? b1 : b0);
            int rr = m & 3;
            int bb = m >> 2;
            float hval = tanhf(v + bs);
            __hip_atomic_store(out + ((size_t)(bgb + bb) * TT + t) * NN + (n0 + rr),
                               hval, __ATOMIC_RELAXED, __HIP_MEMORY_SCOPE_AGENT);
        }

        asm volatile("s_waitcnt vmcnt(0)" ::: "memory");  // h_t stores durable
        __syncthreads();                                  // S2: WG drained
        if (tid == 0) {
            __hip_atomic_store(&gflags[ig], (unsigned)(t + 1),
                               __ATOMIC_RELAXED, __HIP_MEMORY_SCOPE_AGENT);
        }

        up0 += II; up1 += II; up2 += II; up3 += II;
        hp0 += NN; hp1 += NN; hp2 += NN; hp3 += NN;
    }
#undef UPART
#undef DOT
#undef QSTEP
}

extern "C" void kernel_launch(void* const* d_in, const int* in_sizes, int n_in,
                              void* d_out, int out_size, void* d_ws, size_t ws_size,
                              hipStream_t stream) {
    const float* u      = (const float*)d_in[0];
    const float* w_in   = (const float*)d_in[1];
    const float* w      = (const float*)d_in[2];
    const float* w_bias = (const float*)d_in[3];
    float* out          = (float*)d_out;
    unsigned int* flags = (unsigned int*)d_ws;

    hipMemsetAsync(flags, 0, 4 * 64 * sizeof(unsigned int), stream);

    // 256 WGs x 512 threads, 96 KB LDS = exactly 1 WG/CU -> co-residency
    // guaranteed, flag spin cannot deadlock.
    esn_kernel<<<dim3(NWG), dim3(NTHR), 0, stream>>>(u, w_in, w, w_bias, out, flags);
}